// Round 1
// 129.143 us; speedup vs baseline: 1.1210x; 1.1210x over previous
//
#include <hip/hip_runtime.h>

#define BM 128
#define BN 128
#define NSPLIT 8
#define TEMP 0.07f

typedef __attribute__((ext_vector_type(4))) float f32x4;
typedef __attribute__((ext_vector_type(4))) int   i32x4;
typedef __attribute__((ext_vector_type(8))) int   i32x8;

// L2-normalize rows of X (fp32, N x 512), emit fp8 e4m3 (1 B/elem). One wave/row.
__global__ __launch_bounds__(256) void knorm(const float* __restrict__ X,
                                             unsigned char* __restrict__ Fq, int D) {
  int row = blockIdx.x * 4 + (threadIdx.x >> 6);
  int lane = threadIdx.x & 63;
  const float4* xr = (const float4*)(X + (size_t)row * D);
  float4 a = xr[lane * 2];
  float4 b = xr[lane * 2 + 1];
  float ss = a.x*a.x + a.y*a.y + a.z*a.z + a.w*a.w
           + b.x*b.x + b.y*b.y + b.z*b.z + b.w*b.w;
  #pragma unroll
  for (int off = 1; off < 64; off <<= 1) ss += __shfl_xor(ss, off, 64);
  float r = rsqrtf(ss);
  int lo = 0, hi = 0;
  lo = __builtin_amdgcn_cvt_pk_fp8_f32(a.x*r, a.y*r, lo, false);
  lo = __builtin_amdgcn_cvt_pk_fp8_f32(a.z*r, a.w*r, lo, true);
  hi = __builtin_amdgcn_cvt_pk_fp8_f32(b.x*r, b.y*r, hi, false);
  hi = __builtin_amdgcn_cvt_pk_fp8_f32(b.z*r, b.w*r, hi, true);
  int2 o = make_int2(lo, hi);
  *(int2*)(Fq + (size_t)row * D + lane * 8) = o;
}

// Fused sim-tile GEMM + exp/mask row accumulation, fp8 e4m3 inputs.
// MX-scaled MFMA (16x16x128 f8f6f4, all scales = 1.0 -> bit-identical to
// non-scaled e4m3, but 2x the matrix rate: ~4.66 PF vs ~2.1 PF ubench).
// A resident in registers: 32 rows x 512 k per wave = 64 VGPRs (fp8).
// B staged through 64 KB LDS (full K=512). 16B slots XOR-swizzled by the
// LOW 3 row bits only (p = s ^ (row&7)): spreads the b128 column reads
// across all 8 bank-quads, and makes the read-side swizzle a per-lane
// CONSTANT (row&7 == l15&7 for every ni), so every inner-loop ds_read is
// base_vgpr + compile-time immediate (ni*8192 + ks*128 <= 57728 < 64K).
__global__ __launch_bounds__(256, 1)
void kmain(const unsigned char* __restrict__ F, const int* __restrict__ tgt,
           float* __restrict__ psum, float* __restrict__ pmask, int N, int D) {
  __shared__ __align__(16) unsigned char Bs[BN * 512];   // 128 rows x 512 B = 64 KB

  const int tid  = threadIdx.x;
  const int lane = tid & 63;
  const int wave = tid >> 6;
  const int quad = lane >> 4;
  const int l15  = lane & 15;

  const int rowblk   = blockIdx.x / NSPLIT;
  const int split    = blockIdx.x % NSPLIT;   // aligns with XCD round-robin -> L2 reuse
  const int rowbase  = rowblk * BM;
  const int colbase0 = split * (N / NSPLIT);

  // ---- A fragments, loaded once: 2 mi x 4 ksteps x 32 fp8 (i32x8) ----
  // 16x16x128 layout: lane holds row l&15, k = (l>>4)*32 + [0..31] per kstep.
  i32x8 af[2][4];
  #pragma unroll
  for (int mi = 0; mi < 2; ++mi) {
    const unsigned char* rp = F + (size_t)(rowbase + wave*32 + mi*16 + l15) * 512 + quad*32;
    #pragma unroll
    for (int ks = 0; ks < 4; ++ks) {
      i32x4 lo = *(const i32x4*)(rp + ks*128);
      i32x4 hi = *(const i32x4*)(rp + ks*128 + 16);
      af[mi][ks] = __builtin_shufflevector(lo, hi, 0,1,2,3,4,5,6,7);
    }
  }

  int trow[2][4];
  #pragma unroll
  for (int mi = 0; mi < 2; ++mi)
    #pragma unroll
    for (int r = 0; r < 4; ++r)
      trow[mi][r] = tgt[rowbase + wave*32 + mi*16 + quad*4 + r];

  float se[2][4], ms[2][4];
  #pragma unroll
  for (int mi = 0; mi < 2; ++mi)
    #pragma unroll
    for (int r = 0; r < 4; ++r) { se[mi][r] = 0.f; ms[mi][r] = 0.f; }

  const float C1 = (1.0f / TEMP) * 1.4426950408889634f;  // invT*log2(e)
  const float C0 = -C1;

  // Per-lane LDS read bases (constant across tiles/ni/ks):
  // logical slot s = ks*8 + quad*2 + j  ->  phys = ks*8 + ((quad*2+j)^(l15&7))
  const int sw0 = (quad * 2) ^ (l15 & 7);
  const unsigned char* bp0 = Bs + l15*512 + sw0*16;
  const unsigned char* bp1 = Bs + l15*512 + (sw0 ^ 1)*16;

  const int CT = (N / NSPLIT) / BN;   // 8
  for (int ct = 0; ct < CT; ++ct) {
    const int colbase = colbase0 + ct * BN;

    f32x4 acc[2][8];
    #pragma unroll
    for (int mi = 0; mi < 2; ++mi)
      #pragma unroll
      for (int ni = 0; ni < 8; ++ni)
        acc[mi][ni] = (f32x4){0.f, 0.f, 0.f, 0.f};

    __syncthreads();
    // stage B tile (128 rows x 512 B). phys 16B-slot p holds logical slot p^(row&7).
    #pragma unroll
    for (int it = 0; it < 16; ++it) {
      const int L   = it * 256 + tid;   // phys 16B-slot linear index
      const int row = L >> 5;           // 32 slots per row
      const int ks  = (L & 31) ^ (row & 7);
      const unsigned char* g = F + (size_t)(colbase + row) * 512 + ks * 16;
      __builtin_amdgcn_global_load_lds(
          (const __attribute__((address_space(1))) void*)g,
          (__attribute__((address_space(3))) void*)(Bs + L * 16), 16, 0, 0);
    }
    __syncthreads();

    #pragma unroll
    for (int ks = 0; ks < 4; ++ks) {
      #pragma unroll
      for (int ni = 0; ni < 8; ++ni) {
        i32x4 b0 = *(const i32x4*)(bp0 + ni*8192 + ks*128);
        i32x4 b1 = *(const i32x4*)(bp1 + ni*8192 + ks*128);
        i32x8 b = __builtin_shufflevector(b0, b1, 0,1,2,3,4,5,6,7);
        acc[0][ni] = __builtin_amdgcn_mfma_scale_f32_16x16x128_f8f6f4(
            af[0][ks], b, acc[0][ni], 0, 0, 0, 0x7F7F7F7F, 0, 0x7F7F7F7F);
        acc[1][ni] = __builtin_amdgcn_mfma_scale_f32_16x16x128_f8f6f4(
            af[1][ks], b, acc[1][ni], 0, 0, 0, 0x7F7F7F7F, 0, 0x7F7F7F7F);
      }
    }

    // epilogue: fold the 32x128 tile into per-row partial sums
    int tc[8];
    #pragma unroll
    for (int ni = 0; ni < 8; ++ni) tc[ni] = tgt[colbase + ni*16 + l15];
    #pragma unroll
    for (int mi = 0; mi < 2; ++mi)
      #pragma unroll
      for (int ni = 0; ni < 8; ++ni)
        #pragma unroll
        for (int r = 0; r < 4; ++r) {
          float v = acc[mi][ni][r];                 // raw dot in [-1,1]
          se[mi][r] += __builtin_amdgcn_exp2f(fmaf(v, C1, C0));
          if (tc[ni] == trow[mi][r]) ms[mi][r] += v;  // diagonal removed in kfinal
        }
  }

  // reduce across the 16 lanes of each quad (cols), write per-row partials
  #pragma unroll
  for (int mi = 0; mi < 2; ++mi)
    #pragma unroll
    for (int r = 0; r < 4; ++r) {
      float s = se[mi][r], m = ms[mi][r];
      #pragma unroll
      for (int off = 1; off < 16; off <<= 1) {
        s += __shfl_xor(s, off, 64);
        m += __shfl_xor(m, off, 64);
      }
      if (l15 == 0) {
        int row = rowbase + wave*32 + mi*16 + quad*4 + r;
        psum[(size_t)split * N + row]  = s;
        pmask[(size_t)split * N + row] = m;
      }
    }
}

// finalize: 32 blocks x 256 rows each; per-block histogram (targets are L2-hot),
// per-row term, wave reduce, one atomicAdd per block into pre-zeroed out.
__global__ __launch_bounds__(256) void kfinal(
    const float* __restrict__ psum, const float* __restrict__ pmask,
    const int* __restrict__ tgt, float* __restrict__ out, int N) {
  __shared__ int h[128];
  __shared__ float wsum[4];
  const int tid = threadIdx.x;
  if (tid < 128) h[tid] = 0;
  __syncthreads();
  for (int i = tid; i < N; i += 256) atomicAdd(&h[tgt[i] & 127], 1);
  __syncthreads();

  const int i = blockIdx.x * 256 + tid;
  float s = 0.f, m = 0.f;
  #pragma unroll
  for (int sp = 0; sp < NSPLIT; ++sp) {
    s += psum[(size_t)sp * N + i];
    m += pmask[(size_t)sp * N + i];
  }
  const float invT = 1.0f / TEMP;
  float cnt = (float)(h[tgt[i] & 127] - 1);
  // LSE_i = invT + log(s);  sum_mask sim = (m - selfdot(~1.0)) * invT
  float term = (m - 1.0f) * invT / cnt - (logf(s) + invT);
  #pragma unroll
  for (int off = 1; off < 64; off <<= 1) term += __shfl_xor(term, off, 64);
  if ((tid & 63) == 0) wsum[tid >> 6] = term;
  __syncthreads();
  if (tid == 0)
    atomicAdd(out, -(wsum[0] + wsum[1] + wsum[2] + wsum[3]) / (float)N);
}

extern "C" void kernel_launch(void* const* d_in, const int* in_sizes, int n_in,
                              void* d_out, int out_size, void* d_ws, size_t ws_size,
                              hipStream_t stream) {
  const float* X  = (const float*)d_in[0];
  const int* tgt  = (const int*)d_in[1];
  float* out      = (float*)d_out;
  const int N = in_sizes[1];
  const int D = in_sizes[0] / N;

  char* w = (char*)d_ws;
  unsigned char* Fq = (unsigned char*)w;
  size_t off = (size_t)N * D;                          // fp8: 1 B/elem
  float* psum  = (float*)(w + off); off += (size_t)NSPLIT * N * sizeof(float);
  float* pmask = (float*)(w + off);

  hipMemsetAsync(d_out, 0, sizeof(float), stream);
  knorm<<<N / 4, 256, 0, stream>>>(X, Fq, D);
  kmain<<<(N / BM) * NSPLIT, 256, 0, stream>>>(Fq, tgt, psum, pmask, N, D);
  kfinal<<<N / 256, 256, 0, stream>>>(psum, pmask, tgt, out, N);
}

// Round 2
// 114.919 us; speedup vs baseline: 1.2598x; 1.1238x over previous
//
#include <hip/hip_runtime.h>

#define BM 128
#define BN 128
#define HBN 64
#define NSPLIT 8
#define TEMP 0.07f

typedef __attribute__((ext_vector_type(4))) float f32x4;
typedef __attribute__((ext_vector_type(4))) int   i32x4;
typedef __attribute__((ext_vector_type(8))) int   i32x8;

// L2-normalize rows of X (fp32, N x 512), emit fp8 e4m3 (1 B/elem). One wave/row.
__global__ __launch_bounds__(256) void knorm(const float* __restrict__ X,
                                             unsigned char* __restrict__ Fq, int D) {
  int row = blockIdx.x * 4 + (threadIdx.x >> 6);
  int lane = threadIdx.x & 63;
  const float4* xr = (const float4*)(X + (size_t)row * D);
  float4 a = xr[lane * 2];
  float4 b = xr[lane * 2 + 1];
  float ss = a.x*a.x + a.y*a.y + a.z*a.z + a.w*a.w
           + b.x*b.x + b.y*b.y + b.z*b.z + b.w*b.w;
  #pragma unroll
  for (int off = 1; off < 64; off <<= 1) ss += __shfl_xor(ss, off, 64);
  float r = rsqrtf(ss);
  int lo = 0, hi = 0;
  lo = __builtin_amdgcn_cvt_pk_fp8_f32(a.x*r, a.y*r, lo, false);
  lo = __builtin_amdgcn_cvt_pk_fp8_f32(a.z*r, a.w*r, lo, true);
  hi = __builtin_amdgcn_cvt_pk_fp8_f32(b.x*r, b.y*r, hi, false);
  hi = __builtin_amdgcn_cvt_pk_fp8_f32(b.z*r, b.w*r, hi, true);
  int2 o = make_int2(lo, hi);
  *(int2*)(Fq + (size_t)row * D + lane * 8) = o;
}

// Fused sim-tile GEMM + exp/mask row accumulation, fp8 e4m3 inputs.
// MX-scaled MFMA (16x16x128 f8f6f4, scales=1.0 -> bit-identical to e4m3,
// 2x the matrix rate). A resident in registers (32 rows x 512 B / wave).
// R2 structural change: B staged as DOUBLE-BUFFERED 64-col half-tiles
// (2 x 32 KB in the same 64 KB LDS -> 2 blocks/CU kept). Counted
// s_waitcnt vmcnt(8) + raw s_barrier per half-tile: the next half's
// 8 global_load_lds stay in flight across the barrier (T3/T4), removing
// the per-tile vmcnt(0) drain stall of the old __syncthreads() loop.
// Targets for the epilogue are staged into LDS once at prologue so the
// hot loop has NO compiler-visible vector loads (no spurious waits).
__global__ __launch_bounds__(256, 1)
void kmain(const unsigned char* __restrict__ F, const int* __restrict__ tgt,
           float* __restrict__ psum, float* __restrict__ pmask, int N, int D) {
  __shared__ __align__(16) unsigned char Bs[2][HBN * 512];  // 2 x 32 KB
  __shared__ int tgts[1024];                                // N/NSPLIT targets

  const int tid  = threadIdx.x;
  const int lane = tid & 63;
  const int wave = tid >> 6;
  const int quad = lane >> 4;
  const int l15  = lane & 15;

  const int rowblk   = blockIdx.x / NSPLIT;
  const int split    = blockIdx.x % NSPLIT;   // aligns with XCD round-robin -> L2 reuse
  const int rowbase  = rowblk * BM;
  const int colbase0 = split * (N / NSPLIT);
  const int NS       = N / NSPLIT;            // 1024
  const int GT       = NS / HBN;              // 16 half-tiles

  // ---- A fragments, loaded once: 2 mi x 4 ksteps x 32 fp8 (i32x8) ----
  // 16x16x128 layout: lane holds row l&15, k = (l>>4)*32 + [0..31] per kstep.
  i32x8 af[2][4];
  #pragma unroll
  for (int mi = 0; mi < 2; ++mi) {
    const unsigned char* rp = F + (size_t)(rowbase + wave*32 + mi*16 + l15) * 512 + quad*32;
    #pragma unroll
    for (int ks = 0; ks < 4; ++ks) {
      i32x4 lo = *(const i32x4*)(rp + ks*128);
      i32x4 hi = *(const i32x4*)(rp + ks*128 + 16);
      af[mi][ks] = __builtin_shufflevector(lo, hi, 0,1,2,3,4,5,6,7);
    }
  }

  int trow[2][4];
  #pragma unroll
  for (int mi = 0; mi < 2; ++mi)
    #pragma unroll
    for (int r = 0; r < 4; ++r)
      trow[mi][r] = tgt[rowbase + wave*32 + mi*16 + quad*4 + r];

  // stage this split's targets into LDS (read via ds_read in the hot loop)
  for (int i = tid; i < NS; i += 256) tgts[i] = tgt[colbase0 + i];

  float se[2][4], ms[2][4];
  #pragma unroll
  for (int mi = 0; mi < 2; ++mi)
    #pragma unroll
    for (int r = 0; r < 4; ++r) { se[mi][r] = 0.f; ms[mi][r] = 0.f; }

  const float C1 = (1.0f / TEMP) * 1.4426950408889634f;  // invT*log2(e)
  const float C0 = -C1;

  // stage half-tile g (64 rows x 512 B = 32 KB; 8 x 16B slots per thread).
  // phys 16B-slot p within a row holds logical slot p^(row&7) (low 3 bits).
  auto STAGE = [&](int g, int buf) {
    const int cb = colbase0 + g * HBN;
    #pragma unroll
    for (int it = 0; it < 8; ++it) {
      const int L   = it * 256 + tid;   // phys 16B-slot linear index (0..2047)
      const int row = L >> 5;           // 32 slots per row
      const int ks  = (L & 31) ^ (row & 7);
      const unsigned char* gp = F + (size_t)(cb + row) * 512 + ks * 16;
      __builtin_amdgcn_global_load_lds(
          (const __attribute__((address_space(1))) void*)gp,
          (__attribute__((address_space(3))) void*)(&Bs[buf][0] + L * 16), 16, 0, 0);
    }
  };

  // Per-lane read-side swizzle constant: row = ni*16 + l15 -> row&7 == l15&7.
  const int sw0 = (quad * 2) ^ (l15 & 7);

  // full drain: retires af/trow/tgts staging so NO compiler waits land in the loop
  __syncthreads();

  STAGE(0, 0);                               // prologue prefetch (8 in flight)

  for (int g = 0; g < GT; ++g) {
    if (g + 1 < GT) {
      STAGE(g + 1, (g + 1) & 1);             // outstanding <= 16
      asm volatile("s_waitcnt vmcnt(8)" ::: "memory");   // half g landed; next 8 in flight
    } else {
      asm volatile("s_waitcnt vmcnt(0)" ::: "memory");   // last half: full drain
    }
    __builtin_amdgcn_s_barrier();            // all waves see Bs[g&1] staged

    f32x4 acc[2][4];
    #pragma unroll
    for (int mi = 0; mi < 2; ++mi)
      #pragma unroll
      for (int ni = 0; ni < 4; ++ni)
        acc[mi][ni] = (f32x4){0.f, 0.f, 0.f, 0.f};

    const unsigned char* bb  = &Bs[0][0] + (g & 1) * (HBN * 512) + l15 * 512;
    const unsigned char* bp0 = bb + sw0 * 16;
    const unsigned char* bp1 = bb + (sw0 ^ 1) * 16;

    #pragma unroll
    for (int ks = 0; ks < 4; ++ks) {
      #pragma unroll
      for (int ni = 0; ni < 4; ++ni) {
        i32x4 b0 = *(const i32x4*)(bp0 + ni*8192 + ks*128);
        i32x4 b1 = *(const i32x4*)(bp1 + ni*8192 + ks*128);
        i32x8 b = __builtin_shufflevector(b0, b1, 0,1,2,3,4,5,6,7);
        acc[0][ni] = __builtin_amdgcn_mfma_scale_f32_16x16x128_f8f6f4(
            af[0][ks], b, acc[0][ni], 0, 0, 0, 0x7F7F7F7F, 0, 0x7F7F7F7F);
        acc[1][ni] = __builtin_amdgcn_mfma_scale_f32_16x16x128_f8f6f4(
            af[1][ks], b, acc[1][ni], 0, 0, 0, 0x7F7F7F7F, 0, 0x7F7F7F7F);
      }
    }
    __builtin_amdgcn_s_barrier();            // Bs[g&1] reads done before overwrite at g+1

    // epilogue: fold the 32x64 half-tile into per-row partial sums
    int tc[4];
    #pragma unroll
    for (int ni = 0; ni < 4; ++ni) tc[ni] = tgts[g*HBN + ni*16 + l15];
    #pragma unroll
    for (int mi = 0; mi < 2; ++mi)
      #pragma unroll
      for (int ni = 0; ni < 4; ++ni)
        #pragma unroll
        for (int r = 0; r < 4; ++r) {
          float v = acc[mi][ni][r];                 // raw dot in [-1,1]
          se[mi][r] += __builtin_amdgcn_exp2f(fmaf(v, C1, C0));
          if (tc[ni] == trow[mi][r]) ms[mi][r] += v;  // diagonal removed in kfinal
        }
  }

  // reduce across the 16 lanes of each quad (cols), write per-row partials
  #pragma unroll
  for (int mi = 0; mi < 2; ++mi)
    #pragma unroll
    for (int r = 0; r < 4; ++r) {
      float s = se[mi][r], m = ms[mi][r];
      #pragma unroll
      for (int off = 1; off < 16; off <<= 1) {
        s += __shfl_xor(s, off, 64);
        m += __shfl_xor(m, off, 64);
      }
      if (l15 == 0) {
        int row = rowbase + wave*32 + mi*16 + quad*4 + r;
        psum[(size_t)split * N + row]  = s;
        pmask[(size_t)split * N + row] = m;
      }
    }
}

// finalize: 32 blocks x 256 rows each; per-block histogram (targets are L2-hot),
// per-row term, wave reduce, one atomicAdd per block into pre-zeroed out.
__global__ __launch_bounds__(256) void kfinal(
    const float* __restrict__ psum, const float* __restrict__ pmask,
    const int* __restrict__ tgt, float* __restrict__ out, int N) {
  __shared__ int h[128];
  __shared__ float wsum[4];
  const int tid = threadIdx.x;
  if (tid < 128) h[tid] = 0;
  __syncthreads();
  for (int i = tid; i < N; i += 256) atomicAdd(&h[tgt[i] & 127], 1);
  __syncthreads();

  const int i = blockIdx.x * 256 + tid;
  float s = 0.f, m = 0.f;
  #pragma unroll
  for (int sp = 0; sp < NSPLIT; ++sp) {
    s += psum[(size_t)sp * N + i];
    m += pmask[(size_t)sp * N + i];
  }
  const float invT = 1.0f / TEMP;
  float cnt = (float)(h[tgt[i] & 127] - 1);
  // LSE_i = invT + log(s);  sum_mask sim = (m - selfdot(~1.0)) * invT
  float term = (m - 1.0f) * invT / cnt - (logf(s) + invT);
  #pragma unroll
  for (int off = 1; off < 64; off <<= 1) term += __shfl_xor(term, off, 64);
  if ((tid & 63) == 0) wsum[tid >> 6] = term;
  __syncthreads();
  if (tid == 0)
    atomicAdd(out, -(wsum[0] + wsum[1] + wsum[2] + wsum[3]) / (float)N);
}

extern "C" void kernel_launch(void* const* d_in, const int* in_sizes, int n_in,
                              void* d_out, int out_size, void* d_ws, size_t ws_size,
                              hipStream_t stream) {
  const float* X  = (const float*)d_in[0];
  const int* tgt  = (const int*)d_in[1];
  float* out      = (float*)d_out;
  const int N = in_sizes[1];
  const int D = in_sizes[0] / N;

  char* w = (char*)d_ws;
  unsigned char* Fq = (unsigned char*)w;
  size_t off = (size_t)N * D;                          // fp8: 1 B/elem
  float* psum  = (float*)(w + off); off += (size_t)NSPLIT * N * sizeof(float);
  float* pmask = (float*)(w + off);

  hipMemsetAsync(d_out, 0, sizeof(float), stream);
  knorm<<<N / 4, 256, 0, stream>>>(X, Fq, D);
  kmain<<<(N / BM) * NSPLIT, 256, 0, stream>>>(Fq, tgt, psum, pmask, N, D);
  kfinal<<<N / 256, 256, 0, stream>>>(psum, pmask, tgt, out, N);
}